// Round 1
// baseline (1176.882 us; speedup 1.0000x reference)
//
#include <hip/hip_runtime.h>
#include <stdint.h>

#define MROWS 8192   // B*S
#define DDIM  2048
#define HDIM  8192

typedef __attribute__((ext_vector_type(8))) short bf16x8;
typedef __attribute__((ext_vector_type(4))) float f32x4;
typedef unsigned short u16;

__device__ __forceinline__ void async_load16(const void* g, void* l) {
  auto gp = reinterpret_cast<const __attribute__((address_space(1))) unsigned int*>(
      reinterpret_cast<uintptr_t>(g));
  auto lp = reinterpret_cast<__attribute__((address_space(3))) unsigned int*>(
      reinterpret_cast<uintptr_t>(l));
  __builtin_amdgcn_global_load_lds(gp, lp, 16, 0, 0);
}

__device__ __forceinline__ u16 f2bf(float f) {
  union { float f; unsigned int u; } v; v.f = f;
  unsigned int r = v.u + 0x7FFF + ((v.u >> 16) & 1);
  return (u16)(r >> 16);
}

// ---------------- sign(w) -> bf16 {+1,-1,0} ----------------
__global__ void sign_bf16_kernel(const float* __restrict__ w, u16* __restrict__ o) {
  const int t = blockIdx.x * 256 + threadIdx.x;
  const float4* w4 = (const float4*)w;
  float4 a = w4[t * 2], b = w4[t * 2 + 1];
  float v[8] = {a.x, a.y, a.z, a.w, b.x, b.y, b.z, b.w};
  union { u16 s[8]; uint4 u; } pk;
#pragma unroll
  for (int i = 0; i < 8; i++)
    pk.s[i] = v[i] > 0.f ? 0x3F80 : (v[i] < 0.f ? 0xBF80 : 0);
  ((uint4*)o)[t] = pk.u;
}

// ---------------- fused layernorm + activation_quant -> bf16 xq ----------------
__global__ void norm_quant_kernel(const float* __restrict__ x, u16* __restrict__ xq) {
  const int row  = blockIdx.x;
  const int tid  = threadIdx.x;
  const int lane = tid & 63, wave = tid >> 6;
  const float4* xr = (const float4*)(x + (size_t)row * DDIM);
  float4 a = xr[tid * 2], b = xr[tid * 2 + 1];
  float v[8] = {a.x, a.y, a.z, a.w, b.x, b.y, b.z, b.w};
  float s1 = 0.f, s2 = 0.f;
#pragma unroll
  for (int i = 0; i < 8; i++) { s1 += v[i]; s2 += v[i] * v[i]; }
#pragma unroll
  for (int o = 1; o < 64; o <<= 1) { s1 += __shfl_xor(s1, o); s2 += __shfl_xor(s2, o); }
  __shared__ float ssum[4], ssq[4], smax[4];
  if (lane == 0) { ssum[wave] = s1; ssq[wave] = s2; }
  __syncthreads();
  s1 = ssum[0] + ssum[1] + ssum[2] + ssum[3];
  s2 = ssq[0] + ssq[1] + ssq[2] + ssq[3];
  const float mean = s1 * (1.f / DDIM);
  const float var  = s2 * (1.f / DDIM) - mean * mean;
  const float rstd = rsqrtf(var + 1e-8f);
  float mx = 0.f;
#pragma unroll
  for (int i = 0; i < 8; i++) { v[i] = (v[i] - mean) * rstd; mx = fmaxf(mx, fabsf(v[i])); }
#pragma unroll
  for (int o = 1; o < 64; o <<= 1) mx = fmaxf(mx, __shfl_xor(mx, o));
  if (lane == 0) smax[wave] = mx;
  __syncthreads();
  mx = fmaxf(fmaxf(smax[0], smax[1]), fmaxf(smax[2], smax[3]));
  const float s   = 127.f / mx;
  const float inv = mx * (1.f / 127.f);
  union { u16 s[8]; uint4 u; } pk;
#pragma unroll
  for (int i = 0; i < 8; i++) {
    float q = rintf(v[i] * s);            // round half-to-even like jnp.round
    q = fminf(fmaxf(q, -128.f), 127.f);
    pk.s[i] = f2bf(q * inv);
  }
  ((uint4*)(xq + (size_t)row * DDIM))[tid] = pk.u;
}

// ---------------- fused GEMM1+2: p = silu(xq@Wg^T) * (xq@Wu^T), bf16 out ----------------
// 128x128 tile, BK=64, 4 waves each 64x64 via 4x4 mfma 16x16x32
__global__ __launch_bounds__(256, 2) void gemm_glu_kernel(
    const u16* __restrict__ A,   // xq [MROWS, DDIM]
    const u16* __restrict__ Bg,  // sign(W_g) [HDIM, DDIM]
    const u16* __restrict__ Bu,  // sign(W_u) [HDIM, DDIM]
    u16* __restrict__ P)         // [MROWS, HDIM]
{
  constexpr int K = DDIM;
  const int n0 = blockIdx.x * 128;
  const int m0 = blockIdx.y * 128;
  const int tid  = threadIdx.x;
  const int lane = tid & 63, wave = tid >> 6;
  const int wm = wave >> 1, wn = wave & 1;
  const int quad = lane >> 4, l16 = lane & 15;

  __shared__ __align__(16) char lds[49152];
  char* lA  = lds;
  char* lBg = lds + 16384;
  char* lBu = lds + 32768;

  f32x4 accg[4][4], accu[4][4];
  const f32x4 zero = {0.f, 0.f, 0.f, 0.f};
#pragma unroll
  for (int i = 0; i < 4; i++)
#pragma unroll
    for (int j = 0; j < 4; j++) { accg[i][j] = zero; accu[i][j] = zero; }

  const int arow = wm * 64 + l16;
  const int brow = wn * 64 + l16;

  for (int k0 = 0; k0 < K; k0 += 64) {
    __syncthreads();
#pragma unroll
    for (int is = 0; is < 4; ++is) {
      const int o  = is * 4096 + tid * 16;
      const int r  = o >> 7;       // tile row
      const int cb = o & 127;      // col byte within 64*2B row
      char* ldst = (char*)(uintptr_t)(is * 4096 + wave * 1024);
      async_load16((const char*)A  + ((size_t)(m0 + r) * K + k0) * 2 + cb, lA  + is * 4096 + wave * 1024);
      async_load16((const char*)Bg + ((size_t)(n0 + r) * K + k0) * 2 + cb, lBg + is * 4096 + wave * 1024);
      async_load16((const char*)Bu + ((size_t)(n0 + r) * K + k0) * 2 + cb, lBu + is * 4096 + wave * 1024);
      (void)ldst;
    }
    __syncthreads();
#pragma unroll
    for (int ks = 0; ks < 2; ++ks) {
      const int koff = ks * 64 + quad * 16;
      bf16x8 a[4], bg[4], bu[4];
#pragma unroll
      for (int i = 0; i < 4; i++) a[i] = *(const bf16x8*)(lA + (arow + i * 16) * 128 + koff);
#pragma unroll
      for (int j = 0; j < 4; j++) {
        bg[j] = *(const bf16x8*)(lBg + (brow + j * 16) * 128 + koff);
        bu[j] = *(const bf16x8*)(lBu + (brow + j * 16) * 128 + koff);
      }
#pragma unroll
      for (int i = 0; i < 4; i++)
#pragma unroll
        for (int j = 0; j < 4; j++) {
          accg[i][j] = __builtin_amdgcn_mfma_f32_16x16x32_bf16(a[i], bg[j], accg[i][j], 0, 0, 0);
          accu[i][j] = __builtin_amdgcn_mfma_f32_16x16x32_bf16(a[i], bu[j], accu[i][j], 0, 0, 0);
        }
    }
  }

  // epilogue: p = silu(g) * u  -> bf16
  const int rbase = m0 + wm * 64 + quad * 4;
  const int cbase = n0 + wn * 64 + l16;
#pragma unroll
  for (int i = 0; i < 4; i++)
#pragma unroll
    for (int j = 0; j < 4; j++)
#pragma unroll
      for (int r = 0; r < 4; r++) {
        float g = accg[i][j][r];
        float u = accu[i][j][r];
        float pv = (g / (1.f + __expf(-g))) * u;
        P[(size_t)(rbase + i * 16 + r) * HDIM + (cbase + j * 16)] = f2bf(pv);
      }
}

// ---------------- GEMM3: out = p @ sign(W_d)^T, fp32 out ----------------
__global__ __launch_bounds__(256, 2) void gemm_out_kernel(
    const u16* __restrict__ A,  // p [MROWS, HDIM]
    const u16* __restrict__ B,  // sign(W_d) [DDIM, HDIM]
    float* __restrict__ C)      // [MROWS, DDIM]
{
  constexpr int K = HDIM;
  const int n0 = blockIdx.x * 128;
  const int m0 = blockIdx.y * 128;
  const int tid  = threadIdx.x;
  const int lane = tid & 63, wave = tid >> 6;
  const int wm = wave >> 1, wn = wave & 1;
  const int quad = lane >> 4, l16 = lane & 15;

  __shared__ __align__(16) char lds[32768];
  char* lA = lds;
  char* lB = lds + 16384;

  f32x4 acc[4][4];
  const f32x4 zero = {0.f, 0.f, 0.f, 0.f};
#pragma unroll
  for (int i = 0; i < 4; i++)
#pragma unroll
    for (int j = 0; j < 4; j++) acc[i][j] = zero;

  const int arow = wm * 64 + l16;
  const int brow = wn * 64 + l16;

  for (int k0 = 0; k0 < K; k0 += 64) {
    __syncthreads();
#pragma unroll
    for (int is = 0; is < 4; ++is) {
      const int o  = is * 4096 + tid * 16;
      const int r  = o >> 7;
      const int cb = o & 127;
      async_load16((const char*)A + ((size_t)(m0 + r) * K + k0) * 2 + cb, lA + is * 4096 + wave * 1024);
      async_load16((const char*)B + ((size_t)(n0 + r) * K + k0) * 2 + cb, lB + is * 4096 + wave * 1024);
    }
    __syncthreads();
#pragma unroll
    for (int ks = 0; ks < 2; ++ks) {
      const int koff = ks * 64 + quad * 16;
      bf16x8 a[4], b[4];
#pragma unroll
      for (int i = 0; i < 4; i++) a[i] = *(const bf16x8*)(lA + (arow + i * 16) * 128 + koff);
#pragma unroll
      for (int j = 0; j < 4; j++) b[j] = *(const bf16x8*)(lB + (brow + j * 16) * 128 + koff);
#pragma unroll
      for (int i = 0; i < 4; i++)
#pragma unroll
        for (int j = 0; j < 4; j++)
          acc[i][j] = __builtin_amdgcn_mfma_f32_16x16x32_bf16(a[i], b[j], acc[i][j], 0, 0, 0);
    }
  }

  const int rbase = m0 + wm * 64 + quad * 4;
  const int cbase = n0 + wn * 64 + l16;
#pragma unroll
  for (int i = 0; i < 4; i++)
#pragma unroll
    for (int j = 0; j < 4; j++)
#pragma unroll
      for (int r = 0; r < 4; r++)
        C[(size_t)(rbase + i * 16 + r) * DDIM + (cbase + j * 16)] = acc[i][j][r];
}

extern "C" void kernel_launch(void* const* d_in, const int* in_sizes, int n_in,
                              void* d_out, int out_size, void* d_ws, size_t ws_size,
                              hipStream_t stream) {
  const float* x  = (const float*)d_in[0];
  const float* Wg = (const float*)d_in[1];
  const float* Wu = (const float*)d_in[2];
  const float* Wd = (const float*)d_in[3];

  char* ws = (char*)d_ws;
  // layout: xq(32MB) | sWg(32MB) | sWu(32MB) | sWd(32MB) | p(128MB) = 256MB total
  u16* xq  = (u16*)(ws);
  u16* sWg = (u16*)(ws + 33554432ull);
  u16* sWu = (u16*)(ws + 67108864ull);
  u16* sWd = (u16*)(ws + 100663296ull);
  u16* p   = (u16*)(ws + 134217728ull);
  float* out = (float*)d_out;

  // sign conversions: each 16,777,216 elements, 8 per thread
  sign_bf16_kernel<<<8192, 256, 0, stream>>>(Wg, sWg);
  sign_bf16_kernel<<<8192, 256, 0, stream>>>(Wu, sWu);
  sign_bf16_kernel<<<8192, 256, 0, stream>>>(Wd, sWd);

  // fused layernorm + quant (one block per row)
  norm_quant_kernel<<<MROWS, 256, 0, stream>>>(x, xq);

  // fused GEMM1+2 + silu*mul -> p
  dim3 g1(HDIM / 128, MROWS / 128);
  gemm_glu_kernel<<<g1, 256, 0, stream>>>(xq, sWg, sWu, p);

  // GEMM3 -> out
  dim3 g2(DDIM / 128, MROWS / 128);
  gemm_out_kernel<<<g2, 256, 0, stream>>>(p, sWd, out);
}

// Round 2
// 807.171 us; speedup vs baseline: 1.4580x; 1.4580x over previous
//
#include <hip/hip_runtime.h>
#include <stdint.h>

#define MROWS 8192   // B*S
#define DDIM  2048
#define HDIM  8192

typedef __attribute__((ext_vector_type(8))) short bf16x8;
typedef __attribute__((ext_vector_type(4))) float f32x4;
typedef __attribute__((ext_vector_type(4))) int   i32x4;
typedef unsigned short u16;

__device__ __forceinline__ void async_load16(const void* g, void* l) {
  auto gp = reinterpret_cast<const __attribute__((address_space(1))) unsigned int*>(
      reinterpret_cast<uintptr_t>(g));
  auto lp = reinterpret_cast<__attribute__((address_space(3))) unsigned int*>(
      reinterpret_cast<uintptr_t>(l));
  __builtin_amdgcn_global_load_lds(gp, lp, 16, 0, 0);
}

__device__ __forceinline__ u16 f2bf(float f) {
  union { float f; unsigned int u; } v; v.f = f;
  unsigned int r = v.u + 0x7FFF + ((v.u >> 16) & 1);
  return (u16)(r >> 16);
}

// ---------------- sign(w) -> int8 {+1,-1,0} ----------------
__global__ void sign_i8_kernel(const float* __restrict__ w, char* __restrict__ o) {
  const int t = blockIdx.x * 256 + threadIdx.x;
  const float4* w4 = (const float4*)w;
  float4 a = w4[t * 2], b = w4[t * 2 + 1];
  float v[8] = {a.x, a.y, a.z, a.w, b.x, b.y, b.z, b.w};
  union { char s[8]; uint2 u; } pk;
#pragma unroll
  for (int i = 0; i < 8; i++)
    pk.s[i] = v[i] > 0.f ? (char)1 : (v[i] < 0.f ? (char)-1 : (char)0);
  ((uint2*)o)[t] = pk.u;
}

// ---------------- sign(w) -> bf16 {+1,-1,0} (for W_d) ----------------
__global__ void sign_bf16_kernel(const float* __restrict__ w, u16* __restrict__ o) {
  const int t = blockIdx.x * 256 + threadIdx.x;
  const float4* w4 = (const float4*)w;
  float4 a = w4[t * 2], b = w4[t * 2 + 1];
  float v[8] = {a.x, a.y, a.z, a.w, b.x, b.y, b.z, b.w};
  union { u16 s[8]; uint4 u; } pk;
#pragma unroll
  for (int i = 0; i < 8; i++)
    pk.s[i] = v[i] > 0.f ? 0x3F80 : (v[i] < 0.f ? 0xBF80 : 0);
  ((uint4*)o)[t] = pk.u;
}

// ---------------- fused layernorm + activation_quant -> int8 q + row scale ----------------
__global__ void norm_quant_i8_kernel(const float* __restrict__ x,
                                     char* __restrict__ q, float* __restrict__ inv) {
  const int row  = blockIdx.x;
  const int tid  = threadIdx.x;
  const int lane = tid & 63, wave = tid >> 6;
  const float4* xr = (const float4*)(x + (size_t)row * DDIM);
  float4 a = xr[tid * 2], b = xr[tid * 2 + 1];
  float v[8] = {a.x, a.y, a.z, a.w, b.x, b.y, b.z, b.w};
  float s1 = 0.f, s2 = 0.f;
#pragma unroll
  for (int i = 0; i < 8; i++) { s1 += v[i]; s2 += v[i] * v[i]; }
#pragma unroll
  for (int o = 1; o < 64; o <<= 1) { s1 += __shfl_xor(s1, o); s2 += __shfl_xor(s2, o); }
  __shared__ float ssum[4], ssq[4], smax[4];
  if (lane == 0) { ssum[wave] = s1; ssq[wave] = s2; }
  __syncthreads();
  s1 = ssum[0] + ssum[1] + ssum[2] + ssum[3];
  s2 = ssq[0] + ssq[1] + ssq[2] + ssq[3];
  const float mean = s1 * (1.f / DDIM);
  const float var  = s2 * (1.f / DDIM) - mean * mean;
  const float rstd = rsqrtf(var + 1e-8f);
  float mx = 0.f;
#pragma unroll
  for (int i = 0; i < 8; i++) { v[i] = (v[i] - mean) * rstd; mx = fmaxf(mx, fabsf(v[i])); }
#pragma unroll
  for (int o = 1; o < 64; o <<= 1) mx = fmaxf(mx, __shfl_xor(mx, o));
  if (lane == 0) smax[wave] = mx;
  __syncthreads();
  mx = fmaxf(fmaxf(smax[0], smax[1]), fmaxf(smax[2], smax[3]));
  const float s = 127.f / mx;
  if (tid == 0) inv[row] = mx * (1.f / 127.f);
  union { char s8[8]; uint2 u; } pk;
#pragma unroll
  for (int i = 0; i < 8; i++) {
    float qq = rintf(v[i] * s);               // round half-to-even like jnp.round
    qq = fminf(fmaxf(qq, -128.f), 127.f);
    pk.s8[i] = (char)(int)qq;
  }
  ((uint2*)(q + (size_t)row * DDIM))[tid] = pk.u;
}

// ---------------- fused GEMM1+2 (int8): p = silu(g)*u, exact integer dot ----------------
// 128x128 tile, BK=128 bytes, 4 waves each 64x64 via 4x4 mfma_i32_16x16x64_i8
// XOR-swizzled LDS (granule ^= row&7) to kill bank conflicts.
__global__ __launch_bounds__(256, 2) void gemm_glu_i8_kernel(
    const char* __restrict__ A,   // q [MROWS, DDIM] int8
    const char* __restrict__ Bg,  // sign(W_g) [HDIM, DDIM] int8
    const char* __restrict__ Bu,  // sign(W_u) [HDIM, DDIM] int8
    const float* __restrict__ inv,
    u16* __restrict__ P)          // [MROWS, HDIM] bf16
{
  constexpr int K = DDIM;         // bytes per row (int8)
  const int n0 = blockIdx.x * 128;
  const int m0 = blockIdx.y * 128;
  const int tid  = threadIdx.x;
  const int lane = tid & 63, wave = tid >> 6;
  const int wm = wave >> 1, wn = wave & 1;
  const int quad = lane >> 4, l16 = lane & 15;

  __shared__ __align__(16) char lds[49152];
  char* lA  = lds;
  char* lBg = lds + 16384;
  char* lBu = lds + 32768;

  i32x4 accg[4][4], accu[4][4];
  const i32x4 zero = {0, 0, 0, 0};
#pragma unroll
  for (int i = 0; i < 4; i++)
#pragma unroll
    for (int j = 0; j < 4; j++) { accg[i][j] = zero; accu[i][j] = zero; }

  const int arow = wm * 64 + l16;
  const int brow = wn * 64 + l16;
  const int aswz = (arow & 7) << 4;
  const int bswz = (brow & 7) << 4;

  for (int k0 = 0; k0 < K; k0 += 128) {
    __syncthreads();
#pragma unroll
    for (int is = 0; is < 4; ++is) {
      const int o   = is * 4096 + tid * 16;
      const int r   = o >> 7;                      // tile row 0..127
      const int cbs = (o & 127) ^ ((r & 7) << 4);  // swizzled byte-in-row
      async_load16(A  + (size_t)(m0 + r) * K + k0 + cbs, lA  + is * 4096 + wave * 1024);
      async_load16(Bg + (size_t)(n0 + r) * K + k0 + cbs, lBg + is * 4096 + wave * 1024);
      async_load16(Bu + (size_t)(n0 + r) * K + k0 + cbs, lBu + is * 4096 + wave * 1024);
    }
    __syncthreads();
#pragma unroll
    for (int ks = 0; ks < 2; ++ks) {
      const int koff = ks * 64 + quad * 16;
      i32x4 a[4], bg[4], bu[4];
#pragma unroll
      for (int i = 0; i < 4; i++)
        a[i] = *(const i32x4*)(lA + (arow + i * 16) * 128 + (koff ^ aswz));
#pragma unroll
      for (int j = 0; j < 4; j++) {
        bg[j] = *(const i32x4*)(lBg + (brow + j * 16) * 128 + (koff ^ bswz));
        bu[j] = *(const i32x4*)(lBu + (brow + j * 16) * 128 + (koff ^ bswz));
      }
#pragma unroll
      for (int i = 0; i < 4; i++)
#pragma unroll
        for (int j = 0; j < 4; j++) {
          accg[i][j] = __builtin_amdgcn_mfma_i32_16x16x64_i8(a[i], bg[j], accg[i][j], 0, 0, 0);
          accu[i][j] = __builtin_amdgcn_mfma_i32_16x16x64_i8(a[i], bu[j], accu[i][j], 0, 0, 0);
        }
    }
  }

  // epilogue: g,u exact ints scaled by row scale; p = silu(g)*u -> bf16
  const int rbase = m0 + wm * 64 + quad * 4;
  const int cbase = n0 + wn * 64 + l16;
#pragma unroll
  for (int i = 0; i < 4; i++) {
    float iv[4];
#pragma unroll
    for (int r = 0; r < 4; r++) iv[r] = inv[rbase + i * 16 + r];
#pragma unroll
    for (int j = 0; j < 4; j++)
#pragma unroll
      for (int r = 0; r < 4; r++) {
        float g = (float)accg[i][j][r] * iv[r];
        float u = (float)accu[i][j][r] * iv[r];
        float pv = (g / (1.f + __expf(-g))) * u;
        P[(size_t)(rbase + i * 16 + r) * HDIM + (cbase + j * 16)] = f2bf(pv);
      }
  }
}

// ---------------- GEMM3: out = p @ sign(W_d)^T, bf16 in / fp32 out, swizzled ----------------
__global__ __launch_bounds__(256, 3) void gemm_out_kernel(
    const u16* __restrict__ A,  // p [MROWS, HDIM]
    const u16* __restrict__ B,  // sign(W_d) [DDIM, HDIM]
    float* __restrict__ C)      // [MROWS, DDIM]
{
  constexpr int K = HDIM;
  const int n0 = blockIdx.x * 128;
  const int m0 = blockIdx.y * 128;
  const int tid  = threadIdx.x;
  const int lane = tid & 63, wave = tid >> 6;
  const int wm = wave >> 1, wn = wave & 1;
  const int quad = lane >> 4, l16 = lane & 15;

  __shared__ __align__(16) char lds[32768];
  char* lA = lds;
  char* lB = lds + 16384;

  f32x4 acc[4][4];
  const f32x4 zero = {0.f, 0.f, 0.f, 0.f};
#pragma unroll
  for (int i = 0; i < 4; i++)
#pragma unroll
    for (int j = 0; j < 4; j++) acc[i][j] = zero;

  const int arow = wm * 64 + l16;
  const int brow = wn * 64 + l16;
  const int aswz = (arow & 7) << 4;
  const int bswz = (brow & 7) << 4;

  for (int k0 = 0; k0 < K; k0 += 64) {
    __syncthreads();
#pragma unroll
    for (int is = 0; is < 4; ++is) {
      const int o   = is * 4096 + tid * 16;
      const int r   = o >> 7;
      const int cbs = (o & 127) ^ ((r & 7) << 4);
      async_load16((const char*)A + ((size_t)(m0 + r) * K + k0) * 2 + cbs, lA + is * 4096 + wave * 1024);
      async_load16((const char*)B + ((size_t)(n0 + r) * K + k0) * 2 + cbs, lB + is * 4096 + wave * 1024);
    }
    __syncthreads();
#pragma unroll
    for (int ks = 0; ks < 2; ++ks) {
      const int koff = ks * 64 + quad * 16;  // bytes within 128B row
      bf16x8 a[4], b[4];
#pragma unroll
      for (int i = 0; i < 4; i++)
        a[i] = *(const bf16x8*)(lA + (arow + i * 16) * 128 + (koff ^ aswz));
#pragma unroll
      for (int j = 0; j < 4; j++)
        b[j] = *(const bf16x8*)(lB + (brow + j * 16) * 128 + (koff ^ bswz));
#pragma unroll
      for (int i = 0; i < 4; i++)
#pragma unroll
        for (int j = 0; j < 4; j++)
          acc[i][j] = __builtin_amdgcn_mfma_f32_16x16x32_bf16(a[i], b[j], acc[i][j], 0, 0, 0);
    }
  }

  const int rbase = m0 + wm * 64 + quad * 4;
  const int cbase = n0 + wn * 64 + l16;
#pragma unroll
  for (int i = 0; i < 4; i++)
#pragma unroll
    for (int j = 0; j < 4; j++)
#pragma unroll
      for (int r = 0; r < 4; r++)
        C[(size_t)(rbase + i * 16 + r) * DDIM + (cbase + j * 16)] = acc[i][j][r];
}

extern "C" void kernel_launch(void* const* d_in, const int* in_sizes, int n_in,
                              void* d_out, int out_size, void* d_ws, size_t ws_size,
                              hipStream_t stream) {
  const float* x  = (const float*)d_in[0];
  const float* Wg = (const float*)d_in[1];
  const float* Wu = (const float*)d_in[2];
  const float* Wd = (const float*)d_in[3];

  char* ws = (char*)d_ws;
  // layout: q(16MB) | inv(32KB @16MB) | sWg_i8(16MB @20MB) | sWu_i8(16MB @36MB)
  //         | sWd_bf16(32MB @52MB) | p(128MB @84MB)  -> 212MB total
  char*  q    = ws;
  float* inv  = (float*)(ws + 16777216ull);
  char*  sWg  = ws + 20971520ull;
  char*  sWu  = ws + 37748736ull;
  u16*   sWd  = (u16*)(ws + 54525952ull);
  u16*   p    = (u16*)(ws + 88080384ull);
  float* out  = (float*)d_out;

  sign_i8_kernel<<<8192, 256, 0, stream>>>(Wg, sWg);
  sign_i8_kernel<<<8192, 256, 0, stream>>>(Wu, sWu);
  sign_bf16_kernel<<<8192, 256, 0, stream>>>(Wd, sWd);

  norm_quant_i8_kernel<<<MROWS, 256, 0, stream>>>(x, q, inv);

  dim3 g1(HDIM / 128, MROWS / 128);
  gemm_glu_i8_kernel<<<g1, 256, 0, stream>>>(q, sWg, sWu, inv, p);

  dim3 g2(DDIM / 128, MROWS / 128);
  gemm_out_kernel<<<g2, 256, 0, stream>>>(p, sWd, out);
}

// Round 3
// 757.832 us; speedup vs baseline: 1.5530x; 1.0651x over previous
//
#include <hip/hip_runtime.h>
#include <stdint.h>

#define MROWS 8192   // B*S
#define DDIM  2048
#define HDIM  8192

typedef __attribute__((ext_vector_type(8))) short bf16x8;
typedef __attribute__((ext_vector_type(4))) float f32x4;
typedef __attribute__((ext_vector_type(4))) int   i32x4;
typedef unsigned short u16;

__device__ __forceinline__ void async_load16(const void* g, void* l) {
  auto gp = reinterpret_cast<const __attribute__((address_space(1))) unsigned int*>(
      reinterpret_cast<uintptr_t>(g));
  auto lp = reinterpret_cast<__attribute__((address_space(3))) unsigned int*>(
      reinterpret_cast<uintptr_t>(l));
  __builtin_amdgcn_global_load_lds(gp, lp, 16, 0, 0);
}

__device__ __forceinline__ u16 f2bf(float f) {
  union { float f; unsigned int u; } v; v.f = f;
  unsigned int r = v.u + 0x7FFF + ((v.u >> 16) & 1);
  return (u16)(r >> 16);
}

// ---------------- sign(w) -> int8 {+1,-1,0}; blockIdx.y picks Wg/Wu ----------------
__global__ void sign_i8x2_kernel(const float* __restrict__ wg, const float* __restrict__ wu,
                                 char* __restrict__ og, char* __restrict__ ou) {
  const int t = blockIdx.x * 256 + threadIdx.x;
  const float* w = blockIdx.y ? wu : wg;
  char* o = blockIdx.y ? ou : og;
  const float4* w4 = (const float4*)w;
  float4 a = w4[t * 2], b = w4[t * 2 + 1];
  float v[8] = {a.x, a.y, a.z, a.w, b.x, b.y, b.z, b.w};
  union { char s[8]; uint2 u; } pk;
#pragma unroll
  for (int i = 0; i < 8; i++)
    pk.s[i] = v[i] > 0.f ? (char)1 : (v[i] < 0.f ? (char)-1 : (char)0);
  ((uint2*)o)[t] = pk.u;
}

// ---------------- sign(w) -> bf16 {+1,-1,0} (for W_d) ----------------
__global__ void sign_bf16_kernel(const float* __restrict__ w, u16* __restrict__ o) {
  const int t = blockIdx.x * 256 + threadIdx.x;
  const float4* w4 = (const float4*)w;
  float4 a = w4[t * 2], b = w4[t * 2 + 1];
  float v[8] = {a.x, a.y, a.z, a.w, b.x, b.y, b.z, b.w};
  union { u16 s[8]; uint4 u; } pk;
#pragma unroll
  for (int i = 0; i < 8; i++)
    pk.s[i] = v[i] > 0.f ? 0x3F80 : (v[i] < 0.f ? 0xBF80 : 0);
  ((uint4*)o)[t] = pk.u;
}

// ---------------- fused layernorm + activation_quant -> int8 q + row scale ----------------
__global__ void norm_quant_i8_kernel(const float* __restrict__ x,
                                     char* __restrict__ q, float* __restrict__ inv) {
  const int row  = blockIdx.x;
  const int tid  = threadIdx.x;
  const int lane = tid & 63, wave = tid >> 6;
  const float4* xr = (const float4*)(x + (size_t)row * DDIM);
  float4 a = xr[tid * 2], b = xr[tid * 2 + 1];
  float v[8] = {a.x, a.y, a.z, a.w, b.x, b.y, b.z, b.w};
  float s1 = 0.f, s2 = 0.f;
#pragma unroll
  for (int i = 0; i < 8; i++) { s1 += v[i]; s2 += v[i] * v[i]; }
#pragma unroll
  for (int o = 1; o < 64; o <<= 1) { s1 += __shfl_xor(s1, o); s2 += __shfl_xor(s2, o); }
  __shared__ float ssum[4], ssq[4], smax[4];
  if (lane == 0) { ssum[wave] = s1; ssq[wave] = s2; }
  __syncthreads();
  s1 = ssum[0] + ssum[1] + ssum[2] + ssum[3];
  s2 = ssq[0] + ssq[1] + ssq[2] + ssq[3];
  const float mean = s1 * (1.f / DDIM);
  const float var  = s2 * (1.f / DDIM) - mean * mean;
  const float rstd = rsqrtf(var + 1e-8f);
  float mx = 0.f;
#pragma unroll
  for (int i = 0; i < 8; i++) { v[i] = (v[i] - mean) * rstd; mx = fmaxf(mx, fabsf(v[i])); }
#pragma unroll
  for (int o = 1; o < 64; o <<= 1) mx = fmaxf(mx, __shfl_xor(mx, o));
  if (lane == 0) smax[wave] = mx;
  __syncthreads();
  mx = fmaxf(fmaxf(smax[0], smax[1]), fmaxf(smax[2], smax[3]));
  const float s = 127.f / mx;
  if (tid == 0) inv[row] = mx * (1.f / 127.f);
  union { char s8[8]; uint2 u; } pk;
#pragma unroll
  for (int i = 0; i < 8; i++) {
    float qq = rintf(v[i] * s);               // round half-to-even like jnp.round
    qq = fminf(fmaxf(qq, -128.f), 127.f);
    pk.s8[i] = (char)(int)qq;
  }
  ((uint2*)(q + (size_t)row * DDIM))[tid] = pk.u;
}

// ---------------- fused GEMM1+2 (int8): p = silu(g)*u, exact integer dot ----------------
// 128x128 tile, BK=128 bytes, XOR-swizzled LDS, XCD-rect block swizzle.
__global__ __launch_bounds__(256, 2) void gemm_glu_i8_kernel(
    const char* __restrict__ A,   // q [MROWS, DDIM] int8
    const char* __restrict__ Bg,  // sign(W_g) [HDIM, DDIM] int8
    const char* __restrict__ Bu,  // sign(W_u) [HDIM, DDIM] int8
    const float* __restrict__ inv,
    u16* __restrict__ P)          // [MROWS, HDIM] bf16
{
  constexpr int K = DDIM;         // bytes per row (int8)
  // XCD-aware swizzle: XCD x owns n-tiles [8x, 8x+8); consecutive slots share m-stripe.
  const int l   = blockIdx.x + gridDim.x * blockIdx.y;  // 0..4095
  const int xcd = l & 7;
  const int s_  = l >> 3;                               // 0..511
  const int n0 = (xcd * 8 + (s_ & 7)) * 128;
  const int m0 = (s_ >> 3) * 128;
  const int tid  = threadIdx.x;
  const int lane = tid & 63, wave = tid >> 6;
  const int wm = wave >> 1, wn = wave & 1;
  const int quad = lane >> 4, l16 = lane & 15;

  __shared__ __align__(16) char lds[49152];
  char* lA  = lds;
  char* lBg = lds + 16384;
  char* lBu = lds + 32768;

  i32x4 accg[4][4], accu[4][4];
  const i32x4 zero = {0, 0, 0, 0};
#pragma unroll
  for (int i = 0; i < 4; i++)
#pragma unroll
    for (int j = 0; j < 4; j++) { accg[i][j] = zero; accu[i][j] = zero; }

  const int arow = wm * 64 + l16;
  const int brow = wn * 64 + l16;
  const int aswz = (arow & 7) << 4;
  const int bswz = (brow & 7) << 4;

  for (int k0 = 0; k0 < K; k0 += 128) {
    __syncthreads();
#pragma unroll
    for (int is = 0; is < 4; ++is) {
      const int o   = is * 4096 + tid * 16;
      const int r   = o >> 7;                      // tile row 0..127
      const int cbs = (o & 127) ^ ((r & 7) << 4);  // swizzled byte-in-row
      async_load16(A  + (size_t)(m0 + r) * K + k0 + cbs, lA  + is * 4096 + wave * 1024);
      async_load16(Bg + (size_t)(n0 + r) * K + k0 + cbs, lBg + is * 4096 + wave * 1024);
      async_load16(Bu + (size_t)(n0 + r) * K + k0 + cbs, lBu + is * 4096 + wave * 1024);
    }
    __syncthreads();
#pragma unroll
    for (int ks = 0; ks < 2; ++ks) {
      const int koff = ks * 64 + quad * 16;
      i32x4 a[4], bg[4], bu[4];
#pragma unroll
      for (int i = 0; i < 4; i++)
        a[i] = *(const i32x4*)(lA + (arow + i * 16) * 128 + (koff ^ aswz));
#pragma unroll
      for (int j = 0; j < 4; j++) {
        bg[j] = *(const i32x4*)(lBg + (brow + j * 16) * 128 + (koff ^ bswz));
        bu[j] = *(const i32x4*)(lBu + (brow + j * 16) * 128 + (koff ^ bswz));
      }
#pragma unroll
      for (int i = 0; i < 4; i++)
#pragma unroll
        for (int j = 0; j < 4; j++) {
          accg[i][j] = __builtin_amdgcn_mfma_i32_16x16x64_i8(a[i], bg[j], accg[i][j], 0, 0, 0);
          accu[i][j] = __builtin_amdgcn_mfma_i32_16x16x64_i8(a[i], bu[j], accu[i][j], 0, 0, 0);
        }
    }
  }

  // epilogue: g,u exact ints scaled by row scale; p = silu(g)*u -> bf16
  const int rbase = m0 + wm * 64 + quad * 4;
  const int cbase = n0 + wn * 64 + l16;
#pragma unroll
  for (int i = 0; i < 4; i++) {
    float iv[4];
#pragma unroll
    for (int r = 0; r < 4; r++) iv[r] = inv[rbase + i * 16 + r];
#pragma unroll
    for (int j = 0; j < 4; j++)
#pragma unroll
      for (int r = 0; r < 4; r++) {
        float g = (float)accg[i][j][r] * iv[r];
        float u = (float)accu[i][j][r] * iv[r];
        float pv = (g / (1.f + __expf(-g))) * u;
        P[(size_t)(rbase + i * 16 + r) * HDIM + (cbase + j * 16)] = f2bf(pv);
      }
  }
}

// ---------------- GEMM3: out = p @ sign(W_d)^T, bf16 in / fp32 out ----------------
// XCD-rect swizzle: XCD x owns an 8n x 16m rectangle (L2 fill 48MB vs 132MB).
__global__ __launch_bounds__(256, 4) void gemm_out_kernel(
    const u16* __restrict__ A,  // p [MROWS, HDIM]
    const u16* __restrict__ B,  // sign(W_d) [DDIM, HDIM]
    float* __restrict__ C)      // [MROWS, DDIM]
{
  constexpr int K = HDIM;
  const int l   = blockIdx.x + gridDim.x * blockIdx.y;  // 0..1023
  const int xcd = l & 7;
  const int s_  = l >> 3;                               // 0..127
  const int n0 = ((xcd & 1) * 8 + (s_ & 7)) * 128;      // 16 n-tiles
  const int m0 = ((xcd >> 1) * 16 + (s_ >> 3)) * 128;   // 64 m-tiles
  const int tid  = threadIdx.x;
  const int lane = tid & 63, wave = tid >> 6;
  const int wm = wave >> 1, wn = wave & 1;
  const int quad = lane >> 4, l16 = lane & 15;

  __shared__ __align__(16) char lds[32768];
  char* lA = lds;
  char* lB = lds + 16384;

  f32x4 acc[4][4];
  const f32x4 zero = {0.f, 0.f, 0.f, 0.f};
#pragma unroll
  for (int i = 0; i < 4; i++)
#pragma unroll
    for (int j = 0; j < 4; j++) acc[i][j] = zero;

  const int arow = wm * 64 + l16;
  const int brow = wn * 64 + l16;
  const int aswz = (arow & 7) << 4;
  const int bswz = (brow & 7) << 4;

  for (int k0 = 0; k0 < K; k0 += 64) {
    __syncthreads();
#pragma unroll
    for (int is = 0; is < 4; ++is) {
      const int o   = is * 4096 + tid * 16;
      const int r   = o >> 7;
      const int cbs = (o & 127) ^ ((r & 7) << 4);
      async_load16((const char*)A + ((size_t)(m0 + r) * K + k0) * 2 + cbs, lA + is * 4096 + wave * 1024);
      async_load16((const char*)B + ((size_t)(n0 + r) * K + k0) * 2 + cbs, lB + is * 4096 + wave * 1024);
    }
    __syncthreads();
#pragma unroll
    for (int ks = 0; ks < 2; ++ks) {
      const int koff = ks * 64 + quad * 16;  // bytes within 128B row
      bf16x8 a[4], b[4];
#pragma unroll
      for (int i = 0; i < 4; i++)
        a[i] = *(const bf16x8*)(lA + (arow + i * 16) * 128 + (koff ^ aswz));
#pragma unroll
      for (int j = 0; j < 4; j++)
        b[j] = *(const bf16x8*)(lB + (brow + j * 16) * 128 + (koff ^ bswz));
#pragma unroll
      for (int i = 0; i < 4; i++)
#pragma unroll
        for (int j = 0; j < 4; j++)
          acc[i][j] = __builtin_amdgcn_mfma_f32_16x16x32_bf16(a[i], b[j], acc[i][j], 0, 0, 0);
    }
  }

  const int rbase = m0 + wm * 64 + quad * 4;
  const int cbase = n0 + wn * 64 + l16;
#pragma unroll
  for (int i = 0; i < 4; i++)
#pragma unroll
    for (int j = 0; j < 4; j++)
#pragma unroll
      for (int r = 0; r < 4; r++)
        C[(size_t)(rbase + i * 16 + r) * DDIM + (cbase + j * 16)] = acc[i][j][r];
}

extern "C" void kernel_launch(void* const* d_in, const int* in_sizes, int n_in,
                              void* d_out, int out_size, void* d_ws, size_t ws_size,
                              hipStream_t stream) {
  const float* x  = (const float*)d_in[0];
  const float* Wg = (const float*)d_in[1];
  const float* Wu = (const float*)d_in[2];
  const float* Wd = (const float*)d_in[3];

  char* ws = (char*)d_ws;
  // layout: q(16MB) | inv(32KB @16MB) | sWg_i8(16MB @20MB) | sWu_i8(16MB @36MB)
  //         | sWd_bf16(32MB @52MB) | p(128MB @84MB)  -> 212MB total
  char*  q    = ws;
  float* inv  = (float*)(ws + 16777216ull);
  char*  sWg  = ws + 20971520ull;
  char*  sWu  = ws + 37748736ull;
  u16*   sWd  = (u16*)(ws + 54525952ull);
  u16*   p    = (u16*)(ws + 88080384ull);
  float* out  = (float*)d_out;

  dim3 gs(8192, 2);
  sign_i8x2_kernel<<<gs, 256, 0, stream>>>(Wg, Wu, sWg, sWu);
  sign_bf16_kernel<<<8192, 256, 0, stream>>>(Wd, sWd);

  norm_quant_i8_kernel<<<MROWS, 256, 0, stream>>>(x, q, inv);

  dim3 g1(HDIM / 128, MROWS / 128);
  gemm_glu_i8_kernel<<<g1, 256, 0, stream>>>(q, sWg, sWu, inv, p);

  dim3 g2(DDIM / 128, MROWS / 128);
  gemm_out_kernel<<<g2, 256, 0, stream>>>(p, sWd, out);
}